// Round 1
// baseline (487.340 us; speedup 1.0000x reference)
//
#include <hip/hip_runtime.h>
#include <hip/hip_bf16.h>

// CapsuleLayer dynamic routing, recompute-u_hat strategy.
// B=512, R=1152, C=10, O=16, I=8, ROUTING_ITERS=3.
// ws layout (floats): s[81920] | v[81920] | b_ij[512*1152*10]

#define BB   512
#define RR   1152
#define CC   10
#define OO   16
#define II   8
#define CO   160      // C*O
#define BT   4        // batches per block
#define RT   16       // routes per block
#define UP   168      // padded LDS row stride (160 would be 32-bank aligned)
#define NB_B (BB/BT)  // 128
#define NB_R (RR/RT)  // 72

__global__ __launch_bounds__(256) void route_pass(
    const float* __restrict__ x, const float* __restrict__ W,
    const float* __restrict__ v_in, float* __restrict__ b_ij,
    float* __restrict__ s_out, int K)
{
    __shared__ float u_tile[BT * RT * UP];   // 43008 B
    __shared__ float sm[RT][CC];             // logits
    __shared__ float c_lds[RT][CC];          // routing coeffs
    __shared__ float v_lds[CO];

    const int t = threadIdx.x;
    const int bb = blockIdx.x % NB_B;
    const int rc = blockIdx.x / NB_B;
    const int b0 = bb * BT;
    const int r0 = rc * RT;

    const int rr     = t >> 4;   // 0..15 (route within chunk)
    const int lane16 = t & 15;

    // ---------- Phase A: u_tile[bt][rr][co] = sum_i W[r,co,i] * x[b,r,i] ----------
    float xr[BT][II];
    #pragma unroll
    for (int bt = 0; bt < BT; ++bt) {
        const float4* xp = reinterpret_cast<const float4*>(
            x + ((size_t)(b0 + bt) * RR + (r0 + rr)) * II);
        float4 x0 = xp[0], x1 = xp[1];
        xr[bt][0] = x0.x; xr[bt][1] = x0.y; xr[bt][2] = x0.z; xr[bt][3] = x0.w;
        xr[bt][4] = x1.x; xr[bt][5] = x1.y; xr[bt][6] = x1.z; xr[bt][7] = x1.w;
    }
    #pragma unroll
    for (int j = 0; j < 10; ++j) {
        const int co = lane16 + 16 * j;       // 0..159
        const float4* wp = reinterpret_cast<const float4*>(
            W + ((size_t)(r0 + rr) * CO + co) * II);
        float4 w0 = wp[0], w1 = wp[1];
        #pragma unroll
        for (int bt = 0; bt < BT; ++bt) {
            float u = w0.x * xr[bt][0] + w0.y * xr[bt][1] + w0.z * xr[bt][2] + w0.w * xr[bt][3]
                    + w1.x * xr[bt][4] + w1.y * xr[bt][5] + w1.z * xr[bt][6] + w1.w * xr[bt][7];
            u_tile[(bt * RT + rr) * UP + co] = u;
        }
    }
    __syncthreads();

    for (int bt = 0; bt < BT; ++bt) {
        const int b = b0 + bt;
        if (K > 0) {
            if (t < CO) v_lds[t] = v_in[(size_t)b * CO + t];
            __syncthreads();
            // agreement a[rr][c] = sum_o u*v ; lanes: o = lane16, butterfly over 16
            {
                const int o = lane16;
                #pragma unroll
                for (int c = 0; c < CC; ++c) {
                    float p = u_tile[(bt * RT + rr) * UP + c * 16 + o] * v_lds[c * 16 + o];
                    p += __shfl_xor(p, 1);
                    p += __shfl_xor(p, 2);
                    p += __shfl_xor(p, 4);
                    p += __shfl_xor(p, 8);
                    if (o == c) sm[rr][c] = p;   // one lane per (rr,c)
                }
            }
            __syncthreads();
            // b_ij update
            if (lane16 < CC) {
                const size_t gi = ((size_t)b * RR + (r0 + rr)) * CC + lane16;
                float a = sm[rr][lane16];
                float bprev = (K == 2) ? b_ij[gi] : 0.0f;
                float bnew = a + bprev;
                if (K == 1) b_ij[gi] = bnew;   // needed by next iteration only
                sm[rr][lane16] = bnew;
            }
            __syncthreads();
            // softmax over capsules
            if (lane16 < CC) {
                float m = -1e30f;
                #pragma unroll
                for (int c = 0; c < CC; ++c) m = fmaxf(m, sm[rr][c]);
                float sum = 0.0f;
                #pragma unroll
                for (int c = 0; c < CC; ++c) sum += __expf(sm[rr][c] - m);
                c_lds[rr][lane16] = __expf(sm[rr][lane16] - m) / sum;
            }
            __syncthreads();
        }
        // ---------- Phase C: s[b][co] += sum_rr c_ij[rr][c] * u_tile[bt][rr][co] ----------
        if (t < CO) {
            const int c = t >> 4;
            float acc = 0.0f;
            #pragma unroll
            for (int r2 = 0; r2 < RT; ++r2) {
                float cw = (K == 0) ? 0.1f : c_lds[r2][c];
                acc += cw * u_tile[(bt * RT + r2) * UP + t];
            }
            atomicAdd(&s_out[(size_t)b * CO + t], acc);
        }
        __syncthreads();
    }
}

__global__ __launch_bounds__(256) void squash_kernel(
    const float* __restrict__ s, const float* __restrict__ bias,
    float* __restrict__ v_out)
{
    const int idx = blockIdx.x * 256 + threadIdx.x;   // < 81920
    const int co = idx % CO;
    float sv = s[idx] + bias[co];
    float n2 = sv * sv;
    n2 += __shfl_xor(n2, 1);
    n2 += __shfl_xor(n2, 2);
    n2 += __shfl_xor(n2, 4);
    n2 += __shfl_xor(n2, 8);
    float norm = sqrtf(n2);
    float scale = norm / (1.0f + n2 + 1e-8f);
    v_out[idx] = scale * sv;
}

extern "C" void kernel_launch(void* const* d_in, const int* in_sizes, int n_in,
                              void* d_out, int out_size, void* d_ws, size_t ws_size,
                              hipStream_t stream) {
    const float* x    = (const float*)d_in[0];
    const float* W    = (const float*)d_in[1];
    const float* bias = (const float*)d_in[2];
    float* out = (float*)d_out;

    float* s   = (float*)d_ws;          // 81920 floats
    float* v   = s + BB * CO;           // 81920 floats
    float* bij = v + BB * CO;           // 512*1152*10 floats

    const dim3 blk(256);
    const dim3 rgrid(NB_B * NB_R);      // 9216

    for (int K = 0; K < 3; ++K) {
        hipMemsetAsync(s, 0, (size_t)BB * CO * sizeof(float), stream);
        route_pass<<<rgrid, blk, 0, stream>>>(x, W, v, bij, s, K);
        float* vout = (K == 2) ? out : v;
        squash_kernel<<<320, 256, 0, stream>>>(s, bias, vout);
    }
}